// Round 3
// baseline (100.377 us; speedup 1.0000x reference)
//
#include <hip/hip_runtime.h>
#include <hip/hip_bf16.h>

// Problem constants (fixed by setup_inputs)
#define B_N     64
#define C_ORIG  448
#define C_SEL   100
#define CPD     112      // packed channel count in D (16B-aligned rows, zeros at 100..111)
#define HW      3136     // 56*56
#define IMG     224

typedef short bf16x8 __attribute__((ext_vector_type(8)));
typedef float f32x4  __attribute__((ext_vector_type(4)));
typedef unsigned int u32x4 __attribute__((ext_vector_type(4)));

// packed f32 pair -> bf16x2 (compiles to v_cvt_pk_bf16_f32, RNE)
static __device__ __forceinline__ unsigned pkbf(float x, float y) {
    union { __hip_bfloat162 h; unsigned u; } c;
    c.h = __float22bfloat162_rn(float2{x, y});
    return c.u;
}
static __device__ __forceinline__ float bf2f(unsigned short h) {
    return __uint_as_float(((unsigned int)h) << 16);
}

// ---------------------------------------------------------------------------
// Kernel A: gather selected channels, subtract mean (direct loads, L2-hot),
// bf16-cast, transpose to D[p][b][c0..111] (c 100..111 = 0).
// LDS: 16KB transpose tile, swizzle: 8B unit u of row p at byte (8u)^((p&31)<<3).
// One barrier total.
// ---------------------------------------------------------------------------
__global__ __launch_bounds__(256) void kA_gather(const float* __restrict__ feats,
                                                 const float* __restrict__ mean,
                                                 const int* __restrict__ sel,
                                                 unsigned short* __restrict__ D)
{
    __shared__ unsigned short Dt[64 * 128];   // 16 KB
    char* DtB = reinterpret_cast<char*>(Dt);
    const int tid = threadIdx.x;
    const int p0  = blockIdx.x * 64;
    const int b   = blockIdx.y;

    // zero pad units 25..27 (c 100..111) for all 64 rows — disjoint from data bytes
    if (tid < 192) {
        int pr = tid / 3, un = 25 + tid % 3;
        *reinterpret_cast<uint2*>(DtB + pr * 256 + ((8 * un) ^ ((pr & 31) << 3)))
            = make_uint2(0u, 0u);
    }

    const int w    = tid >> 6;
    const int lane = tid & 63;
    const float* fb   = feats + (size_t)b * (C_ORIG * HW) + p0 + lane;
    const float* mrow = mean + (size_t)(p0 + lane) * C_SEL;
    const unsigned swz = (unsigned)(lane & 31) << 3;
    char* rowB = DtB + lane * 256;

    auto quad = [&](int c0) {
        int ch0 = sel[c0], ch1 = sel[c0 + 1], ch2 = sel[c0 + 2], ch3 = sel[c0 + 3];
        float4 m4 = *reinterpret_cast<const float4*>(mrow + c0);
        float v0 = fb[(size_t)ch0 * HW] - m4.x;
        float v1 = fb[(size_t)ch1 * HW] - m4.y;
        float v2 = fb[(size_t)ch2 * HW] - m4.z;
        float v3 = fb[(size_t)ch3 * HW] - m4.w;
        uint2 pk = make_uint2(pkbf(v0, v1), pkbf(v2, v3));
        *reinterpret_cast<uint2*>(rowB + (((unsigned)(2 * c0)) ^ swz)) = pk;
    };

    if (w < 3) {
#pragma unroll
        for (int q = 0; q < 6; ++q) quad(w * 24 + q * 4);   // waves 0-2: 24 ch each
    } else {
#pragma unroll
        for (int q = 0; q < 7; ++q) quad(72 + q * 4);       // wave 3: 28 ch
    }
    __syncthreads();

    // un-swizzle + write D rows (14 x 16B slots per p, coalesced)
    unsigned short* Dp = D + ((size_t)p0 * B_N + b) * CPD;
#pragma unroll
    for (int q = 0; q < 4; ++q) {
        int unit = tid + q * 256;       // 0..895
        if (unit < 896) {
            int pr = unit / 14;
            int s  = unit % 14;
            unsigned off = ((unsigned)(16 * s)) ^ ((((unsigned)pr & 31u) << 3) & 0xF0u);
            uint4 v = *reinterpret_cast<const uint4*>(DtB + pr * 256 + off);
            uint4 r = (pr & 1) ? make_uint4(v.z, v.w, v.x, v.y) : v;
            *reinterpret_cast<uint4*>(reinterpret_cast<char*>(Dp)
                + (size_t)pr * (B_N * CPD * 2) + s * 16) = r;
        }
    }
}

// ---------------------------------------------------------------------------
// Kernel B: per-pixel Mahalanobis, NO LDS. A-fragments (icov rows) loaded
// directly from global f32 and cvt_pk'ed to bf16 in registers; the 4 waves
// read the same 40KB stream (L1/L2 dedup). Rows i>=100 predicated to 0;
// k-slice 96..127 built as [c96..99, 0...] so D's pad region is multiplied
// by A=0. dist written TRANSPOSED as dist[b][p] for kC coalescing.
// ---------------------------------------------------------------------------
__global__ __launch_bounds__(256, 4) void kB_maha(const float* __restrict__ icov,
                                                  const unsigned short* __restrict__ D,
                                                  float* __restrict__ dist)
{
    const int tid  = threadIdx.x;
    const int p    = blockIdx.x;
    const int w    = tid >> 6;
    const int lane = tid & 63;
    const int lrow = lane & 15;
    const int g    = lane >> 4;
    const int bcol = w * 16 + lrow;
    const unsigned short* Drow = D + ((size_t)p * B_N + bcol) * CPD;

    // B-fragments + epilogue D values (one 224B row per lane, read once)
    bf16x8 bfr[4];
#pragma unroll
    for (int ks = 0; ks < 4; ++ks)
        bfr[ks] = *reinterpret_cast<const bf16x8*>(Drow + ks * 32 + g * 8);
    ushort4 dvec[7];
#pragma unroll
    for (int it = 0; it < 7; ++it)
        dvec[it] = *reinterpret_cast<const ushort4*>(Drow + it * 16 + g * 4);

    const float* Mp = icov + (size_t)p * (C_SEL * C_SEL);

    f32x4 acc[7];
#pragma unroll
    for (int it = 0; it < 7; ++it) acc[it] = (f32x4){0.f, 0.f, 0.f, 0.f};

#pragma unroll
    for (int it = 0; it < 7; ++it) {
        const int i = it * 16 + lrow;
        const bool vr = (it < 6) || (lrow < 4);          // row < 100
        const float* rowp = Mp + (size_t)i * C_SEL;
#pragma unroll
        for (int ks = 0; ks < 3; ++ks) {
            float4 va = make_float4(0.f, 0.f, 0.f, 0.f), vb = va;
            if (vr) {
                va = *reinterpret_cast<const float4*>(rowp + ks * 32 + g * 8);
                vb = *reinterpret_cast<const float4*>(rowp + ks * 32 + g * 8 + 4);
            }
            u32x4 u;
            u[0] = pkbf(va.x, va.y); u[1] = pkbf(va.z, va.w);
            u[2] = pkbf(vb.x, vb.y); u[3] = pkbf(vb.z, vb.w);
            acc[it] = __builtin_amdgcn_mfma_f32_16x16x32_bf16(
                __builtin_bit_cast(bf16x8, u), bfr[ks], acc[it], 0, 0, 0);
        }
        {   // ks=3: k=96..127; only g==0 holds valid data (c96..99), rest 0
            float4 va = make_float4(0.f, 0.f, 0.f, 0.f);
            if (vr && g == 0) va = *reinterpret_cast<const float4*>(rowp + 96);
            u32x4 u;
            u[0] = pkbf(va.x, va.y); u[1] = pkbf(va.z, va.w);
            u[2] = 0u; u[3] = 0u;
            acc[it] = __builtin_amdgcn_mfma_f32_16x16x32_bf16(
                __builtin_bit_cast(bf16x8, u), bfr[3], acc[it], 0, 0, 0);
        }
    }

    // epilogue: dist[b] = sum_i D[b,i] * Z[i,b]; C/D layout col=lane&15, row=g*4+r
    float partial = 0.f;
#pragma unroll
    for (int it = 0; it < 7; ++it) {
#pragma unroll
        for (int r = 0; r < 4; ++r) {
            int i = it * 16 + g * 4 + r;
            if (i < C_SEL) {
                unsigned short dh = (r == 0) ? dvec[it].x : (r == 1) ? dvec[it].y
                                   : (r == 2) ? dvec[it].z : dvec[it].w;
                partial += acc[it][r] * bf2f(dh);
            }
        }
    }
    partial += __shfl_xor(partial, 16);
    partial += __shfl_xor(partial, 32);
    if (g == 0) dist[(size_t)bcol * HW + p] = partial;   // dist[b][p] (transposed)
}

// ---------------------------------------------------------------------------
// Kernel C: bilinear 56 -> 224. 4 outputs/thread (static x-weights), dist in
// [b][p] layout -> stride-1 coalesced reads. float4 stores.
// ---------------------------------------------------------------------------
__global__ __launch_bounds__(256) void kC_resize(const float* __restrict__ dist,
                                                 float* __restrict__ out)
{
    int gid = blockIdx.x * 256 + threadIdx.x;   // 802816 = 64*224*56 exactly
    int m = gid % 56;
    int t = gid / 56;
    int y = t % IMG;
    int b = t / IMG;

    float sy = y * 0.25f - 0.375f;
    float fy0 = floorf(sy);
    float fy = sy - fy0;
    int y0 = max((int)fy0, 0);
    int y1 = min((int)fy0 + 1, 55);
    int xm1 = max(m - 1, 0);
    int xp1 = min(m + 1, 55);

    const float* db = dist + (size_t)b * HW;
    const float* d0 = db + y0 * 56;
    const float* d1 = db + y1 * 56;
    float a0 = d0[xm1], b0 = d0[m], c0 = d0[xp1];
    float a1 = d1[xm1], b1 = d1[m], c1 = d1[xp1];

    float A  = a0 + fy * (a1 - a0);
    float Bv = b0 + fy * (b1 - b0);
    float Cv = c0 + fy * (c1 - c0);

    float4 o;
    o.x = A  + 0.625f * (Bv - A);    // x=4m:   x0=m-1, fx=0.625
    o.y = A  + 0.875f * (Bv - A);    // x=4m+1: fx=0.875
    o.z = Bv + 0.125f * (Cv - Bv);   // x=4m+2: x0=m,   fx=0.125
    o.w = Bv + 0.375f * (Cv - Bv);   // x=4m+3: fx=0.375
    *reinterpret_cast<float4*>(out + ((size_t)b * IMG + y) * IMG + 4 * m) = o;
}

extern "C" void kernel_launch(void* const* d_in, const int* in_sizes, int n_in,
                              void* d_out, int out_size, void* d_ws, size_t ws_size,
                              hipStream_t stream)
{
    const float* feats = (const float*)d_in[0];
    const float* mean  = (const float*)d_in[1];
    const float* icov  = (const float*)d_in[2];
    const int*   sel   = (const int*)d_in[3];
    float* out = (float*)d_out;

    unsigned short* Dws = (unsigned short*)d_ws;                        // 45.0 MB
    float* distws = (float*)((char*)d_ws + (size_t)HW * B_N * CPD * 2); // +803 KB

    dim3 gA(49, B_N);
    kA_gather<<<gA, 256, 0, stream>>>(feats, mean, sel, Dws);
    kB_maha<<<HW, 256, 0, stream>>>(icov, Dws, distws);
    kC_resize<<<3136, 256, 0, stream>>>(distws, out);
}

// Round 4
// 78.422 us; speedup vs baseline: 1.2800x; 1.2800x over previous
//
#include <hip/hip_runtime.h>
#include <hip/hip_bf16.h>

// Problem constants (fixed by setup_inputs)
#define B_N     64
#define C_ORIG  448
#define C_SEL   100
#define CPD     112      // packed channel count in D (16B rows, zeros at 100..111)
#define HW      3136     // 56*56
#define IMG     224

typedef short bf16x8 __attribute__((ext_vector_type(8)));
typedef float f32x4  __attribute__((ext_vector_type(4)));

// packed f32 pair -> bf16x2 (compiles to v_cvt_pk_bf16_f32, RNE)
static __device__ __forceinline__ unsigned pkbf(float x, float y) {
    union { __hip_bfloat162 h; unsigned u; } c;
    c.h = __float22bfloat162_rn(float2{x, y});
    return c.u;
}
static __device__ __forceinline__ float bf2f(unsigned short h) {
    return __uint_as_float(((unsigned int)h) << 16);
}

// ---------------------------------------------------------------------------
// Kernel A: gather selected channels, subtract mean (direct loads, L2-hot),
// bf16-cast, transpose to D[p][b][c], c packed to 112 (zeros at 100..111).
// LDS: 16KB transpose tile; swizzle: 8B unit u of row p at byte (8u)^((p&31)<<3).
// One barrier total.
// ---------------------------------------------------------------------------
__global__ __launch_bounds__(256) void kA_gather(const float* __restrict__ feats,
                                                 const float* __restrict__ mean,
                                                 const int* __restrict__ sel,
                                                 unsigned short* __restrict__ D)
{
    __shared__ unsigned short Dt[64 * 128];   // 16 KB
    char* DtB = reinterpret_cast<char*>(Dt);
    const int tid = threadIdx.x;
    const int p0  = blockIdx.x * 64;
    const int b   = blockIdx.y;

    // zero pad units 25..27 (c 100..111) for all 64 rows — disjoint bytes
    if (tid < 192) {
        int pr = tid / 3, un = 25 + tid % 3;
        *reinterpret_cast<uint2*>(DtB + pr * 256 + ((8 * un) ^ ((pr & 31) << 3)))
            = make_uint2(0u, 0u);
    }

    const int w    = tid >> 6;
    const int lane = tid & 63;
    const float* fb   = feats + (size_t)b * (C_ORIG * HW) + p0 + lane;
    const float* mrow = mean + (size_t)(p0 + lane) * C_SEL;
    const unsigned swz = (unsigned)(lane & 31) << 3;
    char* rowB = DtB + lane * 256;

    auto quad = [&](int c0) {
        int ch0 = sel[c0], ch1 = sel[c0 + 1], ch2 = sel[c0 + 2], ch3 = sel[c0 + 3];
        float4 m4 = *reinterpret_cast<const float4*>(mrow + c0);
        float v0 = fb[(size_t)ch0 * HW] - m4.x;
        float v1 = fb[(size_t)ch1 * HW] - m4.y;
        float v2 = fb[(size_t)ch2 * HW] - m4.z;
        float v3 = fb[(size_t)ch3 * HW] - m4.w;
        uint2 pk = make_uint2(pkbf(v0, v1), pkbf(v2, v3));
        *reinterpret_cast<uint2*>(rowB + (((unsigned)(2 * c0)) ^ swz)) = pk;
    };

    if (w < 3) {
#pragma unroll
        for (int q = 0; q < 6; ++q) quad(w * 24 + q * 4);   // waves 0-2: 24 ch each
    } else {
#pragma unroll
        for (int q = 0; q < 7; ++q) quad(72 + q * 4);       // wave 3: 28 ch
    }
    __syncthreads();

    // un-swizzle + write D rows (14 x 16B slots per p, coalesced)
    unsigned short* Dp = D + ((size_t)p0 * B_N + b) * CPD;
#pragma unroll
    for (int q = 0; q < 4; ++q) {
        int unit = tid + q * 256;       // 0..895
        if (unit < 896) {
            int pr = unit / 14;
            int s  = unit % 14;
            unsigned off = ((unsigned)(16 * s)) ^ ((((unsigned)pr & 31u) << 3) & 0xF0u);
            uint4 v = *reinterpret_cast<const uint4*>(DtB + pr * 256 + off);
            uint4 r = (pr & 1) ? make_uint4(v.z, v.w, v.x, v.y) : v;
            *reinterpret_cast<uint4*>(reinterpret_cast<char*>(Dp)
                + (size_t)pr * (B_N * CPD * 2) + s * 16) = r;
        }
    }
}

// ---------------------------------------------------------------------------
// Kernel B: per-pixel Mahalanobis via MFMA. icov[p] staged once to LDS as
// bf16 (swizzled rows); D-row fragments hoisted to registers before staging
// so they fly under the icov stream. One barrier. dist written as dist[b][p].
// ---------------------------------------------------------------------------
__global__ __launch_bounds__(256, 5) void kB_maha(const float* __restrict__ icov,
                                                  const unsigned short* __restrict__ D,
                                                  float* __restrict__ dist)
{
    __shared__ unsigned short Mb[112 * 128];   // 28672 B, slot-swizzle ((i&7)<<4)
    char* MbB = reinterpret_cast<char*>(Mb);
    const int tid  = threadIdx.x;
    const int p    = blockIdx.x;
    const int w    = tid >> 6;
    const int lane = tid & 63;
    const int lrow = lane & 15;
    const int g    = lane >> 4;
    const int bcol = w * 16 + lrow;
    const unsigned short* Drow = D + ((size_t)p * B_N + bcol) * CPD;

    // hoist all D reads (hide under icov staging)
    bf16x8 bfr[4];
#pragma unroll
    for (int ks = 0; ks < 4; ++ks)
        bfr[ks] = *reinterpret_cast<const bf16x8*>(Drow + ks * 32 + g * 8);
    ushort4 dvec[7];
#pragma unroll
    for (int it = 0; it < 7; ++it)
        dvec[it] = *reinterpret_cast<const ushort4*>(Drow + it * 16 + g * 4);

    // pad zeros: rows 0..99 units 25..31 (700 uint2)
#pragma unroll
    for (int q = 0; q < 3; ++q) {
        int z = tid + q * 256;
        if (z < 700) {
            int i = z / 7, un = 25 + z % 7;
            *reinterpret_cast<uint2*>(MbB + i * 256 + ((8 * un) ^ ((i & 7) << 4)))
                = make_uint2(0u, 0u);
        }
    }
    // pad zeros: rows 100..111 full (384 uint2)
#pragma unroll
    for (int q = 0; q < 2; ++q) {
        int z = tid + q * 256;
        if (z < 384) {
            int i = 100 + (z >> 5), un = z & 31;
            *reinterpret_cast<uint2*>(MbB + i * 256 + ((8 * un) ^ ((i & 7) << 4)))
                = make_uint2(0u, 0u);
        }
    }
    // stage icov[p] -> bf16 LDS (coalesced float4 reads, swizzled uint2 writes)
    const float4* src = reinterpret_cast<const float4*>(icov + (size_t)p * (C_SEL * C_SEL));
#pragma unroll
    for (int q = 0; q < 10; ++q) {
        int idx4 = tid + q * 256;
        if (idx4 < 2500) {
            float4 v = src[idx4];
            int i = idx4 / 25, un = idx4 % 25;
            uint2 pk = make_uint2(pkbf(v.x, v.y), pkbf(v.z, v.w));
            *reinterpret_cast<uint2*>(MbB + i * 256 + ((8 * un) ^ ((i & 7) << 4))) = pk;
        }
    }
    __syncthreads();

    f32x4 acc[7];
#pragma unroll
    for (int it = 0; it < 7; ++it) acc[it] = (f32x4){0.f, 0.f, 0.f, 0.f};

#pragma unroll
    for (int ks = 0; ks < 4; ++ks) {
#pragma unroll
        for (int it = 0; it < 7; ++it) {
            int i = it * 16 + lrow;
            bf16x8 afrag = *reinterpret_cast<const bf16x8*>(
                MbB + i * 256 + ((ks * 64 + g * 16) ^ ((i & 7) << 4)));
            acc[it] = __builtin_amdgcn_mfma_f32_16x16x32_bf16(afrag, bfr[ks], acc[it], 0, 0, 0);
        }
    }

    // epilogue: dist[b] = sum_i D[b,i] * Z[i,b]; C/D layout col=lane&15, row=g*4+r
    float partial = 0.f;
#pragma unroll
    for (int it = 0; it < 7; ++it) {
#pragma unroll
        for (int r = 0; r < 4; ++r) {
            int i = it * 16 + g * 4 + r;
            if (i < C_SEL) {
                unsigned short dh = (r == 0) ? dvec[it].x : (r == 1) ? dvec[it].y
                                   : (r == 2) ? dvec[it].z : dvec[it].w;
                partial += acc[it][r] * bf2f(dh);
            }
        }
    }
    partial += __shfl_xor(partial, 16);
    partial += __shfl_xor(partial, 32);
    if (g == 0) dist[(size_t)bcol * HW + p] = partial;   // dist[b][p] (transposed)
}

// ---------------------------------------------------------------------------
// Kernel C: bilinear 56 -> 224. 4 outputs/thread (static x-weights), dist in
// [b][p] layout -> stride-1 coalesced reads. float4 stores.
// ---------------------------------------------------------------------------
__global__ __launch_bounds__(256) void kC_resize(const float* __restrict__ dist,
                                                 float* __restrict__ out)
{
    int gid = blockIdx.x * 256 + threadIdx.x;   // 802816 = 64*224*56 exactly
    int m = gid % 56;
    int t = gid / 56;
    int y = t % IMG;
    int b = t / IMG;

    float sy = y * 0.25f - 0.375f;
    float fy0 = floorf(sy);
    float fy = sy - fy0;
    int y0 = max((int)fy0, 0);
    int y1 = min((int)fy0 + 1, 55);
    int xm1 = max(m - 1, 0);
    int xp1 = min(m + 1, 55);

    const float* db = dist + (size_t)b * HW;
    const float* d0 = db + y0 * 56;
    const float* d1 = db + y1 * 56;
    float a0 = d0[xm1], b0 = d0[m], c0 = d0[xp1];
    float a1 = d1[xm1], b1 = d1[m], c1 = d1[xp1];

    float A  = a0 + fy * (a1 - a0);
    float Bv = b0 + fy * (b1 - b0);
    float Cv = c0 + fy * (c1 - c0);

    float4 o;
    o.x = A  + 0.625f * (Bv - A);    // x=4m:   x0=m-1, fx=0.625
    o.y = A  + 0.875f * (Bv - A);    // x=4m+1: fx=0.875
    o.z = Bv + 0.125f * (Cv - Bv);   // x=4m+2: x0=m,   fx=0.125
    o.w = Bv + 0.375f * (Cv - Bv);   // x=4m+3: fx=0.375
    *reinterpret_cast<float4*>(out + ((size_t)b * IMG + y) * IMG + 4 * m) = o;
}

extern "C" void kernel_launch(void* const* d_in, const int* in_sizes, int n_in,
                              void* d_out, int out_size, void* d_ws, size_t ws_size,
                              hipStream_t stream)
{
    const float* feats = (const float*)d_in[0];
    const float* mean  = (const float*)d_in[1];
    const float* icov  = (const float*)d_in[2];
    const int*   sel   = (const int*)d_in[3];
    float* out = (float*)d_out;

    unsigned short* Dws = (unsigned short*)d_ws;                        // 45.0 MB
    float* distws = (float*)((char*)d_ws + (size_t)HW * B_N * CPD * 2); // +803 KB

    dim3 gA(49, B_N);
    kA_gather<<<gA, 256, 0, stream>>>(feats, mean, sel, Dws);
    kB_maha<<<HW, 256, 0, stream>>>(icov, Dws, distws);
    kC_resize<<<3136, 256, 0, stream>>>(distws, out);
}

// Round 5
// 76.878 us; speedup vs baseline: 1.3057x; 1.0201x over previous
//
#include <hip/hip_runtime.h>
#include <hip/hip_bf16.h>

// Problem constants (fixed by setup_inputs)
#define B_N     64
#define C_ORIG  448
#define C_SEL   100
#define CPD     112      // packed channel count in D (16B rows, zeros at 100..111)
#define HW      3136     // 56*56
#define IMG     224

typedef short bf16x8 __attribute__((ext_vector_type(8)));
typedef float f32x4  __attribute__((ext_vector_type(4)));

// packed f32 pair -> bf16x2 (compiles to v_cvt_pk_bf16_f32, RNE)
static __device__ __forceinline__ unsigned pkbf(float x, float y) {
    union { __hip_bfloat162 h; unsigned u; } c;
    c.h = __float22bfloat162_rn(float2{x, y});
    return c.u;
}
static __device__ __forceinline__ float bf2f(unsigned short h) {
    return __uint_as_float(((unsigned int)h) << 16);
}

// ---------------------------------------------------------------------------
// Kernel A0: transpose mean[p][c] (400B rows, gather-hostile) to meanT[c][p]
// so kA's mean loads coalesce like its feats loads. 49 blocks, one-shot.
// ---------------------------------------------------------------------------
__global__ __launch_bounds__(256) void kA0_meanT(const float* __restrict__ mean,
                                                 float* __restrict__ meanT)
{
    __shared__ float mt[64 * 100];   // 25.6 KB, mt[p_loc][c] (flat copy of 64 rows)
    const int tid = threadIdx.x;
    const int p0  = blockIdx.x * 64;
    const float4* src = reinterpret_cast<const float4*>(mean + (size_t)p0 * C_SEL);
#pragma unroll
    for (int q = 0; q < 7; ++q) {
        int idx4 = tid + q * 256;
        if (idx4 < 1600) {
            float4 v = src[idx4];
            *reinterpret_cast<float4*>(&mt[idx4 * 4]) = v;
        }
    }
    __syncthreads();
    // unit = c*16 + s : write meanT[c][p0 + s*4 .. +3] (coalesced float4)
#pragma unroll
    for (int q = 0; q < 7; ++q) {
        int u = tid + q * 256;
        if (u < 1600) {
            int c = u >> 4, s = u & 15;
            float4 v;
            v.x = mt[(s * 4 + 0) * 100 + c];
            v.y = mt[(s * 4 + 1) * 100 + c];
            v.z = mt[(s * 4 + 2) * 100 + c];
            v.w = mt[(s * 4 + 3) * 100 + c];
            *reinterpret_cast<float4*>(meanT + (size_t)c * HW + p0 + s * 4) = v;
        }
    }
}

// ---------------------------------------------------------------------------
// Kernel A: gather selected channels, subtract meanT (coalesced, same [ch][HW]
// pattern as feats), bf16-cast, transpose to D[p][b][c] (c packed to 112).
// LDS: 16KB transpose tile; swizzle: 8B unit u of row p at byte (8u)^((p&31)<<3).
// One barrier total.
// ---------------------------------------------------------------------------
__global__ __launch_bounds__(256) void kA_gather(const float* __restrict__ feats,
                                                 const float* __restrict__ meanT,
                                                 const int* __restrict__ sel,
                                                 unsigned short* __restrict__ D)
{
    __shared__ unsigned short Dt[64 * 128];   // 16 KB
    char* DtB = reinterpret_cast<char*>(Dt);
    const int tid = threadIdx.x;
    const int p0  = blockIdx.x * 64;
    const int b   = blockIdx.y;

    // zero pad units 25..27 (c 100..111) for all 64 rows — disjoint bytes
    if (tid < 192) {
        int pr = tid / 3, un = 25 + tid % 3;
        *reinterpret_cast<uint2*>(DtB + pr * 256 + ((8 * un) ^ ((pr & 31) << 3)))
            = make_uint2(0u, 0u);
    }

    const int w    = tid >> 6;
    const int lane = tid & 63;
    const float* fb = feats + (size_t)b * (C_ORIG * HW) + p0 + lane;
    const float* mb = meanT + p0 + lane;
    const unsigned swz = (unsigned)(lane & 31) << 3;
    char* rowB = DtB + lane * 256;

    auto quad = [&](int c0) {
        int ch0 = sel[c0], ch1 = sel[c0 + 1], ch2 = sel[c0 + 2], ch3 = sel[c0 + 3];
        float v0 = fb[(size_t)ch0 * HW] - mb[(size_t)(c0 + 0) * HW];
        float v1 = fb[(size_t)ch1 * HW] - mb[(size_t)(c0 + 1) * HW];
        float v2 = fb[(size_t)ch2 * HW] - mb[(size_t)(c0 + 2) * HW];
        float v3 = fb[(size_t)ch3 * HW] - mb[(size_t)(c0 + 3) * HW];
        uint2 pk = make_uint2(pkbf(v0, v1), pkbf(v2, v3));
        *reinterpret_cast<uint2*>(rowB + (((unsigned)(2 * c0)) ^ swz)) = pk;
    };

    if (w < 3) {
#pragma unroll
        for (int q = 0; q < 6; ++q) quad(w * 24 + q * 4);   // waves 0-2: 24 ch each
    } else {
#pragma unroll
        for (int q = 0; q < 7; ++q) quad(72 + q * 4);       // wave 3: 28 ch
    }
    __syncthreads();

    // un-swizzle + write D rows (14 x 16B slots per p, coalesced)
    unsigned short* Dp = D + ((size_t)p0 * B_N + b) * CPD;
#pragma unroll
    for (int q = 0; q < 4; ++q) {
        int unit = tid + q * 256;       // 0..895
        if (unit < 896) {
            int pr = unit / 14;
            int s  = unit % 14;
            unsigned off = ((unsigned)(16 * s)) ^ ((((unsigned)pr & 31u) << 3) & 0xF0u);
            uint4 v = *reinterpret_cast<const uint4*>(DtB + pr * 256 + off);
            uint4 r = (pr & 1) ? make_uint4(v.z, v.w, v.x, v.y) : v;
            *reinterpret_cast<uint4*>(reinterpret_cast<char*>(Dp)
                + (size_t)pr * (B_N * CPD * 2) + s * 16) = r;
        }
    }
}

// ---------------------------------------------------------------------------
// Kernel B: per-pixel Mahalanobis via MFMA. icov[p] staged once to LDS as
// bf16 (swizzled rows); B-fragments hoisted to registers before staging.
// One barrier. dist written contiguously as dist[p][b] (256B/block).
// ---------------------------------------------------------------------------
__global__ __launch_bounds__(256, 5) void kB_maha(const float* __restrict__ icov,
                                                  const unsigned short* __restrict__ D,
                                                  float* __restrict__ dist)
{
    __shared__ unsigned short Mb[112 * 128];   // 28672 B, slot-swizzle ((i&7)<<4)
    char* MbB = reinterpret_cast<char*>(Mb);
    const int tid  = threadIdx.x;
    const int p    = blockIdx.x;
    const int w    = tid >> 6;
    const int lane = tid & 63;
    const int lrow = lane & 15;
    const int g    = lane >> 4;
    const int bcol = w * 16 + lrow;
    const unsigned short* Drow = D + ((size_t)p * B_N + bcol) * CPD;

    // hoist B-fragment reads (hide under icov staging)
    bf16x8 bfr[4];
#pragma unroll
    for (int ks = 0; ks < 4; ++ks)
        bfr[ks] = *reinterpret_cast<const bf16x8*>(Drow + ks * 32 + g * 8);

    // pad zeros: rows 0..99 units 25..31 (700 uint2)
#pragma unroll
    for (int q = 0; q < 3; ++q) {
        int z = tid + q * 256;
        if (z < 700) {
            int i = z / 7, un = 25 + z % 7;
            *reinterpret_cast<uint2*>(MbB + i * 256 + ((8 * un) ^ ((i & 7) << 4)))
                = make_uint2(0u, 0u);
        }
    }
    // pad zeros: rows 100..111 full (384 uint2)
#pragma unroll
    for (int q = 0; q < 2; ++q) {
        int z = tid + q * 256;
        if (z < 384) {
            int i = 100 + (z >> 5), un = z & 31;
            *reinterpret_cast<uint2*>(MbB + i * 256 + ((8 * un) ^ ((i & 7) << 4)))
                = make_uint2(0u, 0u);
        }
    }
    // stage icov[p] -> bf16 LDS (coalesced float4 reads, swizzled uint2 writes)
    const float4* src = reinterpret_cast<const float4*>(icov + (size_t)p * (C_SEL * C_SEL));
#pragma unroll
    for (int q = 0; q < 10; ++q) {
        int idx4 = tid + q * 256;
        if (idx4 < 2500) {
            float4 v = src[idx4];
            int i = idx4 / 25, un = idx4 % 25;
            uint2 pk = make_uint2(pkbf(v.x, v.y), pkbf(v.z, v.w));
            *reinterpret_cast<uint2*>(MbB + i * 256 + ((8 * un) ^ ((i & 7) << 4))) = pk;
        }
    }
    __syncthreads();

    // epilogue D values loaded post-barrier (L1/L2-hot) to cut staging VGPR pressure
    ushort4 dvec[7];
#pragma unroll
    for (int it = 0; it < 7; ++it)
        dvec[it] = *reinterpret_cast<const ushort4*>(Drow + it * 16 + g * 4);

    f32x4 acc[7];
#pragma unroll
    for (int it = 0; it < 7; ++it) acc[it] = (f32x4){0.f, 0.f, 0.f, 0.f};

#pragma unroll
    for (int ks = 0; ks < 4; ++ks) {
#pragma unroll
        for (int it = 0; it < 7; ++it) {
            int i = it * 16 + lrow;
            bf16x8 afrag = *reinterpret_cast<const bf16x8*>(
                MbB + i * 256 + ((ks * 64 + g * 16) ^ ((i & 7) << 4)));
            acc[it] = __builtin_amdgcn_mfma_f32_16x16x32_bf16(afrag, bfr[ks], acc[it], 0, 0, 0);
        }
    }

    // epilogue: dist[b] = sum_i D[b,i] * Z[i,b]; C/D layout col=lane&15, row=g*4+r
    float partial = 0.f;
#pragma unroll
    for (int it = 0; it < 7; ++it) {
#pragma unroll
        for (int r = 0; r < 4; ++r) {
            int i = it * 16 + g * 4 + r;
            if (i < C_SEL) {
                unsigned short dh = (r == 0) ? dvec[it].x : (r == 1) ? dvec[it].y
                                   : (r == 2) ? dvec[it].z : dvec[it].w;
                partial += acc[it][r] * bf2f(dh);
            }
        }
    }
    partial += __shfl_xor(partial, 16);
    partial += __shfl_xor(partial, 32);
    if (g == 0) dist[p * B_N + bcol] = partial;   // dist[p][b], contiguous 256B/block
}

// ---------------------------------------------------------------------------
// Kernel C: bilinear 56 -> 224 with LDS row staging. Block = output row y:
// stages the two source rows [56p][64b] (coalesced float4 from dist[p][b]),
// computes 64b x 224x outputs with conflict-free LDS reads (66-pad) and
// coalesced float4 stores. grid 224.
// ---------------------------------------------------------------------------
__global__ __launch_bounds__(256) void kC_resize(const float* __restrict__ dist,
                                                 float* __restrict__ out)
{
    __shared__ float L[2 * 56 * 66];   // 29.6 KB, L[r][m][b], pad 66 vs 64
    const int tid = threadIdx.x;
    const int y   = blockIdx.x;

    float sy = y * 0.25f - 0.375f;
    float fy0 = floorf(sy);
    float fy = sy - fy0;
    int y0 = max((int)fy0, 0);
    int y1 = min((int)fy0 + 1, 55);
    int rsrc[2] = {y0, y1};

#pragma unroll
    for (int r = 0; r < 2; ++r) {
        const float4* s4 = reinterpret_cast<const float4*>(dist + (size_t)rsrc[r] * 56 * B_N);
#pragma unroll
        for (int j = 0; j < 4; ++j) {
            int idx = tid + j * 256;
            if (idx < 896) {                 // 896 float4 = 56*64 floats
                float4 v = s4[idx];
                int m  = idx >> 4;
                int b4 = (idx & 15) * 4;
                float* d = &L[r * 56 * 66 + m * 66 + b4];
                d[0] = v.x; d[1] = v.y; d[2] = v.z; d[3] = v.w;
            }
        }
    }
    __syncthreads();

    // unit = b*56 + m : compute out[b][y][4m..4m+3]
#pragma unroll
    for (int j = 0; j < 14; ++j) {
        int unit = tid + j * 256;            // 0..3583 = 64*56
        int b = unit / 56;
        int m = unit % 56;
        int xm1 = max(m - 1, 0);
        int xp1 = min(m + 1, 55);

        const float* L0 = &L[0 * 56 * 66];
        const float* L1 = &L[1 * 56 * 66];
        float a0 = L0[xm1 * 66 + b], b0 = L0[m * 66 + b], c0 = L0[xp1 * 66 + b];
        float a1 = L1[xm1 * 66 + b], b1 = L1[m * 66 + b], c1 = L1[xp1 * 66 + b];

        float A  = a0 + fy * (a1 - a0);
        float Bv = b0 + fy * (b1 - b0);
        float Cv = c0 + fy * (c1 - c0);

        float4 o;
        o.x = A  + 0.625f * (Bv - A);    // x=4m:   x0=m-1, fx=0.625
        o.y = A  + 0.875f * (Bv - A);    // x=4m+1: fx=0.875
        o.z = Bv + 0.125f * (Cv - Bv);   // x=4m+2: x0=m,   fx=0.125
        o.w = Bv + 0.375f * (Cv - Bv);   // x=4m+3: fx=0.375
        *reinterpret_cast<float4*>(out + ((size_t)b * IMG + y) * IMG + 4 * m) = o;
    }
}

extern "C" void kernel_launch(void* const* d_in, const int* in_sizes, int n_in,
                              void* d_out, int out_size, void* d_ws, size_t ws_size,
                              hipStream_t stream)
{
    const float* feats = (const float*)d_in[0];
    const float* mean  = (const float*)d_in[1];
    const float* icov  = (const float*)d_in[2];
    const int*   sel   = (const int*)d_in[3];
    float* out = (float*)d_out;

    char* ws = (char*)d_ws;
    unsigned short* Dws = (unsigned short*)ws;                    // 45.0 MB
    size_t off = (size_t)HW * B_N * CPD * 2;
    float* distws = (float*)(ws + off);                           // +803 KB
    off += (size_t)HW * B_N * 4;
    float* meanT = (float*)(ws + off);                            // +1.25 MB

    kA0_meanT<<<49, 256, 0, stream>>>(mean, meanT);
    dim3 gA(49, B_N);
    kA_gather<<<gA, 256, 0, stream>>>(feats, meanT, sel, Dws);
    kB_maha<<<HW, 256, 0, stream>>>(icov, Dws, distws);
    kC_resize<<<IMG, 256, 0, stream>>>(distws, out);
}